// Round 1
// baseline (290.516 us; speedup 1.0000x reference)
//
#include <hip/hip_runtime.h>
#include <math.h>

#define SDR_DIM 65536
#define HIDDEN  4096
#define NMOD    2048
#define PHASE   4096
#define NORM_EPS 1e-8f

__device__ __forceinline__ float waveReduce(float v) {
  #pragma unroll
  for (int off = 32; off > 0; off >>= 1) v += __shfl_down(v, off);
  return v;
}

// ---------------------------------------------------------------------------
// Kernel 1: compact active indices (deterministic, sorted) + zero accumulators
// 1 block x 1024 threads; thread t owns sdr[t*64 .. t*64+63]
// ---------------------------------------------------------------------------
__global__ __launch_bounds__(1024) void k_compact(const float* __restrict__ sdr,
                                                  int* __restrict__ idx,
                                                  int* __restrict__ nact,
                                                  float* __restrict__ accums) {
  __shared__ int wsum[16];
  int t = threadIdx.x;
  int lane = t & 63, wave = t >> 6;
  int base = t * 64;

  int cnt = 0;
  #pragma unroll
  for (int i = 0; i < 64; ++i) cnt += (sdr[base + i] > 0.0f) ? 1 : 0;

  // inclusive scan within wave
  int inc = cnt;
  #pragma unroll
  for (int d = 1; d < 64; d <<= 1) {
    int v = __shfl_up(inc, d);
    if (lane >= d) inc += v;
  }
  if (lane == 63) wsum[wave] = inc;
  __syncthreads();
  if (t == 0) {
    int s = 0;
    #pragma unroll
    for (int w = 0; w < 16; ++w) { int v = wsum[w]; wsum[w] = s; s += v; }
    *nact = s;
    accums[0] = 0.0f;  // ||z_ego||^2
    accums[1] = 0.0f;  // ||z_fb||^2
  }
  __syncthreads();

  int off = wsum[wave] + (inc - cnt);  // exclusive prefix for this thread
  for (int i = 0; i < 64; ++i) {
    if (sdr[base + i] > 0.0f) idx[off++] = base + i;
  }
}

// ---------------------------------------------------------------------------
// Kernel 2: h = relu(W1 @ sdr + b1) via sparse column gather.
// 1 row per wave, 4 waves per block. 8 gathers in flight per lane.
// ---------------------------------------------------------------------------
__global__ __launch_bounds__(256) void k_h(const float* __restrict__ W1,
                                           const float* __restrict__ b1,
                                           const int* __restrict__ idx,
                                           const int* __restrict__ nactp,
                                           float* __restrict__ h) {
  int lane = threadIdx.x & 63;
  int row = blockIdx.x * 4 + (threadIdx.x >> 6);
  int n = *nactp;
  const float* __restrict__ Wr = W1 + (size_t)row * SDR_DIM;

  float acc = 0.0f;
  int k = lane;
  for (; k + 448 < n; k += 512) {
    int i0 = idx[k];       int i1 = idx[k + 64];
    int i2 = idx[k + 128]; int i3 = idx[k + 192];
    int i4 = idx[k + 256]; int i5 = idx[k + 320];
    int i6 = idx[k + 384]; int i7 = idx[k + 448];
    acc += Wr[i0]; acc += Wr[i1]; acc += Wr[i2]; acc += Wr[i3];
    acc += Wr[i4]; acc += Wr[i5]; acc += Wr[i6]; acc += Wr[i7];
  }
  for (; k < n; k += 64) acc += Wr[idx[k]];

  acc = waveReduce(acc);
  if (lane == 0) {
    float v = acc + b1[row];
    h[row] = v > 0.0f ? v : 0.0f;
  }
}

// ---------------------------------------------------------------------------
// Kernel 3: z_ego = W2 @ h + b2   (dense matvec, float4, 1 row/wave)
// ---------------------------------------------------------------------------
__global__ __launch_bounds__(256) void k_z(const float* __restrict__ W,
                                           const float* __restrict__ x,
                                           const float* __restrict__ b,
                                           float* __restrict__ y) {
  int lane = threadIdx.x & 63;
  int row = blockIdx.x * 4 + (threadIdx.x >> 6);
  const float4* __restrict__ Wr = (const float4*)(W + (size_t)row * HIDDEN);
  const float4* __restrict__ xv = (const float4*)x;
  float acc = 0.0f;
  #pragma unroll 4
  for (int k = lane; k < HIDDEN / 4; k += 64) {
    float4 w = Wr[k]; float4 v = xv[k];
    acc += w.x * v.x + w.y * v.y + w.z * v.z + w.w * v.w;
  }
  acc = waveReduce(acc);
  if (lane == 0) y[row] = acc + b[row];
}

// ---------------------------------------------------------------------------
// Kernel 4: theta = vel_W @ velocity; rotate pairs; accumulate ||z_ego||^2
// ---------------------------------------------------------------------------
__global__ __launch_bounds__(256) void k_rot(const float* __restrict__ zego,
                                             const float* __restrict__ velW,
                                             const float* __restrict__ vel,
                                             float* __restrict__ zflat,
                                             float* __restrict__ accums) {
  int m = blockIdx.x * 256 + threadIdx.x;  // 0..NMOD-1
  int lane = threadIdx.x & 63;
  float v0 = vel[0], v1 = vel[1];
  float th = velW[2 * m] * v0 + velW[2 * m + 1] * v1;
  float s, c;
  sincosf(th, &s, &c);
  float x = zego[2 * m], y = zego[2 * m + 1];
  zflat[2 * m]     = c * x - s * y;
  zflat[2 * m + 1] = s * x + c * y;
  float n2 = x * x + y * y;
  n2 = waveReduce(n2);
  if (lane == 0) atomicAdd(accums + 0, n2);
}

// ---------------------------------------------------------------------------
// Kernel 5: h_new = tanh(W_tc@z_flat + W_ht@h_tc); z_fb = z_flat + 0.1*sig(g)*h_new
//           accumulate ||z_fb||^2. 1 row per wave.
// ---------------------------------------------------------------------------
__global__ __launch_bounds__(256) void k_hnew(const float* __restrict__ Wtc,
                                              const float* __restrict__ Wht,
                                              const float* __restrict__ zflat,
                                              const float* __restrict__ htc,
                                              const float* __restrict__ gnrt,
                                              float* __restrict__ accums,
                                              float* __restrict__ zfb) {
  int lane = threadIdx.x & 63;
  int row = blockIdx.x * 4 + (threadIdx.x >> 6);
  const float4* __restrict__ Ar = (const float4*)(Wtc + (size_t)row * PHASE);
  const float4* __restrict__ Br = (const float4*)(Wht + (size_t)row * PHASE);
  const float4* __restrict__ xv = (const float4*)zflat;
  const float4* __restrict__ hv = (const float4*)htc;
  float acc = 0.0f;
  #pragma unroll 2
  for (int k = lane; k < PHASE / 4; k += 64) {
    float4 a = Ar[k], v = xv[k];
    acc += a.x * v.x + a.y * v.y + a.z * v.z + a.w * v.w;
    float4 bb = Br[k], u = hv[k];
    acc += bb.x * u.x + bb.y * u.y + bb.z * u.z + bb.w * u.w;
  }
  acc = waveReduce(acc);
  if (lane == 0) {
    float hn = tanhf(acc);
    float sg = 1.0f / (1.0f + expf(-gnrt[row]));
    float v = zflat[row] + 0.1f * sg * hn;
    zfb[row] = v;
    atomicAdd(accums + 1, v * v);
  }
}

// ---------------------------------------------------------------------------
// Kernel 6: final rescale with reference `where` semantics
// ---------------------------------------------------------------------------
__global__ __launch_bounds__(256) void k_out(const float* __restrict__ zfb,
                                             const float* __restrict__ accums,
                                             float* __restrict__ out) {
  int i = blockIdx.x * 256 + threadIdx.x;
  float tn = sqrtf(accums[0]);
  float cn = sqrtf(accums[1]);
  float v = zfb[i];
  float r = v * (tn / fmaxf(cn, NORM_EPS));
  float o = (cn > NORM_EPS) ? r : v;
  o = (tn > NORM_EPS) ? o : 0.0f;
  out[i] = o;
}

extern "C" void kernel_launch(void* const* d_in, const int* in_sizes, int n_in,
                              void* d_out, int out_size, void* d_ws, size_t ws_size,
                              hipStream_t stream) {
  const float* sdr  = (const float*)d_in[0];
  const float* vel  = (const float*)d_in[1];
  const float* W1   = (const float*)d_in[2];
  const float* b1   = (const float*)d_in[3];
  const float* W2   = (const float*)d_in[4];
  const float* b2   = (const float*)d_in[5];
  const float* velW = (const float*)d_in[6];
  const float* Wtc  = (const float*)d_in[7];
  const float* Wht  = (const float*)d_in[8];
  const float* gnrt = (const float*)d_in[9];
  const float* htc  = (const float*)d_in[10];
  float* out = (float*)d_out;

  char* ws = (char*)d_ws;
  int*   nact   = (int*)ws;                               // 1 int
  float* accums = (float*)(ws + 16);                      // 2 floats
  int*   idx    = (int*)(ws + 64);                        // up to SDR_DIM ints
  float* h      = (float*)(ws + 64 + SDR_DIM * sizeof(int));
  float* zego   = h + HIDDEN;
  float* zflat  = zego + PHASE;
  float* zfb    = zflat + PHASE;

  k_compact<<<1, 1024, 0, stream>>>(sdr, idx, nact, accums);
  k_h<<<HIDDEN / 4, 256, 0, stream>>>(W1, b1, idx, nact, h);
  k_z<<<PHASE / 4, 256, 0, stream>>>(W2, h, b2, zego);
  k_rot<<<NMOD / 256, 256, 0, stream>>>(zego, velW, vel, zflat, accums);
  k_hnew<<<PHASE / 4, 256, 0, stream>>>(Wtc, Wht, zflat, htc, gnrt, accums, zfb);
  k_out<<<PHASE / 256, 256, 0, stream>>>(zfb, accums, out);
}

// Round 2
// 218.127 us; speedup vs baseline: 1.3319x; 1.3319x over previous
//
#include <hip/hip_runtime.h>
#include <math.h>

#define SDR_DIM 65536
#define HIDDEN  4096
#define NMOD    2048
#define PHASE   4096
#define NGRP_MAX (SDR_DIM / 16)   // 4096 groups of 16 floats (64B lines)
#define NORM_EPS 1e-8f

__device__ __forceinline__ float waveReduce(float v) {
  #pragma unroll
  for (int off = 32; off > 0; off >>= 1) v += __shfl_down(v, off);
  return v;
}

// ---------------------------------------------------------------------------
// Kernel 1: build packed group list. Group g = columns [16g, 16g+16) (one 64B
// line of a W1 row). Entry = (mask16 << 16) | g, emitted in ascending g
// (deterministic). 1 block x 1024 threads; thread t owns groups 4t..4t+3.
// ---------------------------------------------------------------------------
__global__ __launch_bounds__(1024) void k_compact(const float* __restrict__ sdr,
                                                  unsigned int* __restrict__ packed,
                                                  int* __restrict__ ngrp) {
  __shared__ int wsum[16];
  int t = threadIdx.x;
  int lane = t & 63, wave = t >> 6;

  unsigned int masks[4];
  int cnt = 0;
  const float4* s4 = (const float4*)sdr;
  #pragma unroll
  for (int g = 0; g < 4; ++g) {
    int gid = t * 4 + g;
    unsigned int m = 0;
    #pragma unroll
    for (int q = 0; q < 4; ++q) {
      float4 v = s4[gid * 4 + q];
      m |= (v.x > 0.0f ? 1u : 0u) << (q * 4 + 0);
      m |= (v.y > 0.0f ? 1u : 0u) << (q * 4 + 1);
      m |= (v.z > 0.0f ? 1u : 0u) << (q * 4 + 2);
      m |= (v.w > 0.0f ? 1u : 0u) << (q * 4 + 3);
    }
    masks[g] = m;
    cnt += (m != 0u) ? 1 : 0;
  }

  // inclusive scan within wave
  int inc = cnt;
  #pragma unroll
  for (int d = 1; d < 64; d <<= 1) {
    int v = __shfl_up(inc, d);
    if (lane >= d) inc += v;
  }
  if (lane == 63) wsum[wave] = inc;
  __syncthreads();
  if (t == 0) {
    int s = 0;
    #pragma unroll
    for (int w = 0; w < 16; ++w) { int v = wsum[w]; wsum[w] = s; s += v; }
    *ngrp = s;
  }
  __syncthreads();

  int off = wsum[wave] + (inc - cnt);
  #pragma unroll
  for (int g = 0; g < 4; ++g) {
    if (masks[g]) packed[off++] = (masks[g] << 16) | (unsigned int)(t * 4 + g);
  }
}

// ---------------------------------------------------------------------------
// Kernel 2: h = relu(W1 @ sdr + b1), sparse line-streaming.
// 1 row per wave, 4 waves/block. Lane cluster of 4 covers one 64B group:
// slot = lane>>2 picks the packed entry, sub = lane&3 picks the float4.
// Every memory request is a fully-used aligned 64B line.
// ---------------------------------------------------------------------------
__global__ __launch_bounds__(256) void k_h(const float* __restrict__ W1,
                                           const float* __restrict__ b1,
                                           const unsigned int* __restrict__ packed,
                                           const int* __restrict__ ngrpp,
                                           float* __restrict__ h) {
  int lane = threadIdx.x & 63;
  int row = blockIdx.x * 4 + (threadIdx.x >> 6);
  int n = *ngrpp;
  int sub = lane & 3, slot = lane >> 2;
  int shift = 16 + sub * 4;
  const float4* __restrict__ Wr4 = (const float4*)(W1 + (size_t)row * SDR_DIM);

  float acc = 0.0f;
  int k = slot;
  for (; k + 48 < n; k += 64) {
    unsigned int e0 = packed[k];
    unsigned int e1 = packed[k + 16];
    unsigned int e2 = packed[k + 32];
    unsigned int e3 = packed[k + 48];
    float4 f0 = Wr4[(e0 & 0xFFFFu) * 4 + sub];
    float4 f1 = Wr4[(e1 & 0xFFFFu) * 4 + sub];
    float4 f2 = Wr4[(e2 & 0xFFFFu) * 4 + sub];
    float4 f3 = Wr4[(e3 & 0xFFFFu) * 4 + sub];
    unsigned int m0 = (e0 >> shift) & 0xFu;
    unsigned int m1 = (e1 >> shift) & 0xFu;
    unsigned int m2 = (e2 >> shift) & 0xFu;
    unsigned int m3 = (e3 >> shift) & 0xFu;
    acc += (m0 & 1u) ? f0.x : 0.0f; acc += (m0 & 2u) ? f0.y : 0.0f;
    acc += (m0 & 4u) ? f0.z : 0.0f; acc += (m0 & 8u) ? f0.w : 0.0f;
    acc += (m1 & 1u) ? f1.x : 0.0f; acc += (m1 & 2u) ? f1.y : 0.0f;
    acc += (m1 & 4u) ? f1.z : 0.0f; acc += (m1 & 8u) ? f1.w : 0.0f;
    acc += (m2 & 1u) ? f2.x : 0.0f; acc += (m2 & 2u) ? f2.y : 0.0f;
    acc += (m2 & 4u) ? f2.z : 0.0f; acc += (m2 & 8u) ? f2.w : 0.0f;
    acc += (m3 & 1u) ? f3.x : 0.0f; acc += (m3 & 2u) ? f3.y : 0.0f;
    acc += (m3 & 4u) ? f3.z : 0.0f; acc += (m3 & 8u) ? f3.w : 0.0f;
  }
  for (; k < n; k += 16) {
    unsigned int e = packed[k];
    float4 f = Wr4[(e & 0xFFFFu) * 4 + sub];
    unsigned int m = (e >> shift) & 0xFu;
    acc += (m & 1u) ? f.x : 0.0f; acc += (m & 2u) ? f.y : 0.0f;
    acc += (m & 4u) ? f.z : 0.0f; acc += (m & 8u) ? f.w : 0.0f;
  }

  acc = waveReduce(acc);
  if (lane == 0) {
    float v = acc + b1[row];
    h[row] = v > 0.0f ? v : 0.0f;
  }
}

// ---------------------------------------------------------------------------
// Kernel 3: z_ego = W2 @ h + b2 (1 row/wave, float4) fused with the
// per-pair rotation (block owns rows 4b..4b+3 = complete pairs 2b, 2b+1).
// ---------------------------------------------------------------------------
__global__ __launch_bounds__(256) void k_z_rot(const float* __restrict__ W,
                                               const float* __restrict__ x,
                                               const float* __restrict__ b,
                                               const float* __restrict__ velW,
                                               const float* __restrict__ vel,
                                               float* __restrict__ zego,
                                               float* __restrict__ zflat) {
  __shared__ float zs[4];
  int lane = threadIdx.x & 63;
  int wave = threadIdx.x >> 6;
  int row = blockIdx.x * 4 + wave;
  const float4* __restrict__ Wr = (const float4*)(W + (size_t)row * HIDDEN);
  const float4* __restrict__ xv = (const float4*)x;
  float acc = 0.0f;
  #pragma unroll 4
  for (int k = lane; k < HIDDEN / 4; k += 64) {
    float4 w = Wr[k]; float4 v = xv[k];
    acc += w.x * v.x + w.y * v.y + w.z * v.z + w.w * v.w;
  }
  acc = waveReduce(acc);
  if (lane == 0) {
    float v = acc + b[row];
    zego[row] = v;
    zs[wave] = v;
  }
  __syncthreads();
  if (threadIdx.x < 2) {
    int m = blockIdx.x * 2 + threadIdx.x;      // pair index
    float xx = zs[2 * threadIdx.x];
    float yy = zs[2 * threadIdx.x + 1];
    float th = velW[2 * m] * vel[0] + velW[2 * m + 1] * vel[1];
    float s, c;
    sincosf(th, &s, &c);
    zflat[2 * m]     = c * xx - s * yy;
    zflat[2 * m + 1] = s * xx + c * yy;
  }
}

// ---------------------------------------------------------------------------
// Kernel 4: h_new = tanh(W_tc@z_flat + W_ht@h_tc);
//           z_fb = z_flat + 0.1*sigmoid(g_nrt)*h_new.  1 row/wave.
// ---------------------------------------------------------------------------
__global__ __launch_bounds__(256) void k_hnew(const float* __restrict__ Wtc,
                                              const float* __restrict__ Wht,
                                              const float* __restrict__ zflat,
                                              const float* __restrict__ htc,
                                              const float* __restrict__ gnrt,
                                              float* __restrict__ zfb) {
  int lane = threadIdx.x & 63;
  int row = blockIdx.x * 4 + (threadIdx.x >> 6);
  const float4* __restrict__ Ar = (const float4*)(Wtc + (size_t)row * PHASE);
  const float4* __restrict__ Br = (const float4*)(Wht + (size_t)row * PHASE);
  const float4* __restrict__ xv = (const float4*)zflat;
  const float4* __restrict__ hv = (const float4*)htc;
  float acc = 0.0f;
  #pragma unroll 2
  for (int k = lane; k < PHASE / 4; k += 64) {
    float4 a = Ar[k], v = xv[k];
    acc += a.x * v.x + a.y * v.y + a.z * v.z + a.w * v.w;
    float4 bb = Br[k], u = hv[k];
    acc += bb.x * u.x + bb.y * u.y + bb.z * u.z + bb.w * u.w;
  }
  acc = waveReduce(acc);
  if (lane == 0) {
    float hn = tanhf(acc);
    float sg = 1.0f / (1.0f + expf(-gnrt[row]));
    zfb[row] = zflat[row] + 0.1f * sg * hn;
  }
}

// ---------------------------------------------------------------------------
// Kernel 5: single-block deterministic norms + final where/rescale.
// ---------------------------------------------------------------------------
__global__ __launch_bounds__(1024) void k_out(const float* __restrict__ zego,
                                              const float* __restrict__ zfb,
                                              float* __restrict__ out) {
  __shared__ float s0[16], s1[16];
  int t = threadIdx.x;
  int lane = t & 63, wave = t >> 6;
  float a = 0.0f, bsum = 0.0f;
  #pragma unroll
  for (int i = 0; i < PHASE / 1024; ++i) {
    float xe = zego[t + i * 1024]; a += xe * xe;
    float xf = zfb[t + i * 1024];  bsum += xf * xf;
  }
  a = waveReduce(a);
  bsum = waveReduce(bsum);
  if (lane == 0) { s0[wave] = a; s1[wave] = bsum; }
  __syncthreads();
  if (t == 0) {
    float ta = 0.0f, tb = 0.0f;
    #pragma unroll
    for (int w = 0; w < 16; ++w) { ta += s0[w]; tb += s1[w]; }
    s0[0] = ta; s1[0] = tb;
  }
  __syncthreads();
  float tn = sqrtf(s0[0]);
  float cn = sqrtf(s1[0]);
  float scale = tn / fmaxf(cn, NORM_EPS);
  #pragma unroll
  for (int i = 0; i < PHASE / 1024; ++i) {
    float v = zfb[t + i * 1024];
    float r = v * scale;
    float o = (cn > NORM_EPS) ? r : v;
    o = (tn > NORM_EPS) ? o : 0.0f;
    out[t + i * 1024] = o;
  }
}

extern "C" void kernel_launch(void* const* d_in, const int* in_sizes, int n_in,
                              void* d_out, int out_size, void* d_ws, size_t ws_size,
                              hipStream_t stream) {
  const float* sdr  = (const float*)d_in[0];
  const float* vel  = (const float*)d_in[1];
  const float* W1   = (const float*)d_in[2];
  const float* b1   = (const float*)d_in[3];
  const float* W2   = (const float*)d_in[4];
  const float* b2   = (const float*)d_in[5];
  const float* velW = (const float*)d_in[6];
  const float* Wtc  = (const float*)d_in[7];
  const float* Wht  = (const float*)d_in[8];
  const float* gnrt = (const float*)d_in[9];
  const float* htc  = (const float*)d_in[10];
  float* out = (float*)d_out;

  char* ws = (char*)d_ws;
  int* ngrp = (int*)ws;                                   // 1 int (+pad)
  unsigned int* packed = (unsigned int*)(ws + 64);        // NGRP_MAX uints
  float* h     = (float*)(ws + 64 + NGRP_MAX * sizeof(unsigned int));
  float* zego  = h + HIDDEN;
  float* zflat = zego + PHASE;
  float* zfb   = zflat + PHASE;

  k_compact<<<1, 1024, 0, stream>>>(sdr, packed, ngrp);
  k_h<<<HIDDEN / 4, 256, 0, stream>>>(W1, b1, packed, ngrp, h);
  k_z_rot<<<PHASE / 4, 256, 0, stream>>>(W2, h, b2, velW, vel, zego, zflat);
  k_hnew<<<PHASE / 4, 256, 0, stream>>>(Wtc, Wht, zflat, htc, gnrt, zfb);
  k_out<<<1, 1024, 0, stream>>>(zego, zfb, out);
}

// Round 4
// 175.989 us; speedup vs baseline: 1.6508x; 1.2394x over previous
//
#include <hip/hip_runtime.h>
#include <math.h>

#define SDR_DIM 65536
#define HIDDEN  4096
#define NMOD    2048
#define PHASE   4096
#define NGRP    (SDR_DIM / 16)    // 4096 groups of 16 floats (64B lines)
#define NORM_EPS 1e-8f

typedef float fx4 __attribute__((ext_vector_type(4)));

__device__ __forceinline__ float waveReduce(float v) {
  #pragma unroll
  for (int off = 32; off > 0; off >>= 1) v += __shfl_down(v, off);
  return v;
}

__device__ __forceinline__ fx4 ntload4(const fx4* p) {
  return __builtin_nontemporal_load(p);
}

// ---------------------------------------------------------------------------
// Kernel 1a: per-group 16-bit activity masks (parallel over 16 blocks).
// group g = columns [16g, 16g+16) = one 64B line of each W1 row.
// ---------------------------------------------------------------------------
__global__ __launch_bounds__(256) void k_masks(const float* __restrict__ sdr,
                                               unsigned int* __restrict__ masks) {
  int g = blockIdx.x * 256 + threadIdx.x;   // 0..NGRP-1
  const fx4* s4 = (const fx4*)sdr;
  unsigned int m = 0;
  #pragma unroll
  for (int q = 0; q < 4; ++q) {
    fx4 v = s4[g * 4 + q];
    m |= (v.x > 0.0f ? 1u : 0u) << (q * 4 + 0);
    m |= (v.y > 0.0f ? 1u : 0u) << (q * 4 + 1);
    m |= (v.z > 0.0f ? 1u : 0u) << (q * 4 + 2);
    m |= (v.w > 0.0f ? 1u : 0u) << (q * 4 + 3);
  }
  masks[g] = m;
}

// ---------------------------------------------------------------------------
// Kernel 1b: single-block scan over the (L2-hot, 16KB) mask array -> packed
// list (ascending g, deterministic). Also: ntc flag = any(h_tc != 0).
// ---------------------------------------------------------------------------
__global__ __launch_bounds__(1024) void k_emit(const unsigned int* __restrict__ masks,
                                               const float* __restrict__ htc,
                                               unsigned int* __restrict__ packed,
                                               int* __restrict__ ngrp,
                                               int* __restrict__ ntc) {
  __shared__ int wsum[16];
  __shared__ int sflag;
  int t = threadIdx.x;
  int lane = t & 63, wave = t >> 6;
  if (t == 0) sflag = 0;
  __syncthreads();

  // h_tc nonzero check (4096 floats, 4 per thread)
  bool nz = false;
  #pragma unroll
  for (int i = 0; i < PHASE / 1024; ++i) nz |= (htc[t + i * 1024] != 0.0f);
  if (nz) sflag = 1;

  unsigned int m[4];
  int cnt = 0;
  #pragma unroll
  for (int g = 0; g < 4; ++g) {
    m[g] = masks[t * 4 + g];
    cnt += (m[g] != 0u) ? 1 : 0;
  }
  int inc = cnt;
  #pragma unroll
  for (int d = 1; d < 64; d <<= 1) {
    int v = __shfl_up(inc, d);
    if (lane >= d) inc += v;
  }
  if (lane == 63) wsum[wave] = inc;
  __syncthreads();
  if (t == 0) {
    int s = 0;
    #pragma unroll
    for (int w = 0; w < 16; ++w) { int v = wsum[w]; wsum[w] = s; s += v; }
    *ngrp = s;
    *ntc = sflag;
  }
  __syncthreads();
  int off = wsum[wave] + (inc - cnt);
  #pragma unroll
  for (int g = 0; g < 4; ++g) {
    if (m[g]) packed[off++] = (m[g] << 16) | (unsigned int)(t * 4 + g);
  }
}

// ---------------------------------------------------------------------------
// Kernel 2: h = relu(W1 @ sdr + b1), sparse 64B-line streaming.
// 1 row/wave, 4 waves/block. Lane cluster of 4 covers one line; 8 lines in
// flight per lane. Weight loads non-temporal (zero reuse).
// ---------------------------------------------------------------------------
__global__ __launch_bounds__(256) void k_h(const float* __restrict__ W1,
                                           const float* __restrict__ b1,
                                           const unsigned int* __restrict__ packed,
                                           const int* __restrict__ ngrpp,
                                           float* __restrict__ h) {
  int lane = threadIdx.x & 63;
  int row = blockIdx.x * 4 + (threadIdx.x >> 6);
  int n = *ngrpp;
  int sub = lane & 3, slot = lane >> 2;
  int shift = 16 + sub * 4;
  const fx4* __restrict__ Wr4 = (const fx4*)(W1 + (size_t)row * SDR_DIM);

  float acc = 0.0f;
  int k = slot;
  for (; k + 112 < n; k += 128) {
    unsigned int e[8];
    fx4 f[8];
    #pragma unroll
    for (int j = 0; j < 8; ++j) e[j] = packed[k + 16 * j];
    #pragma unroll
    for (int j = 0; j < 8; ++j) f[j] = ntload4(Wr4 + ((e[j] & 0xFFFFu) * 4 + sub));
    #pragma unroll
    for (int j = 0; j < 8; ++j) {
      unsigned int mj = (e[j] >> shift) & 0xFu;
      acc += (mj & 1u) ? f[j].x : 0.0f;
      acc += (mj & 2u) ? f[j].y : 0.0f;
      acc += (mj & 4u) ? f[j].z : 0.0f;
      acc += (mj & 8u) ? f[j].w : 0.0f;
    }
  }
  for (; k < n; k += 16) {
    unsigned int e = packed[k];
    fx4 f = ntload4(Wr4 + ((e & 0xFFFFu) * 4 + sub));
    unsigned int mj = (e >> shift) & 0xFu;
    acc += (mj & 1u) ? f.x : 0.0f;
    acc += (mj & 2u) ? f.y : 0.0f;
    acc += (mj & 4u) ? f.z : 0.0f;
    acc += (mj & 8u) ? f.w : 0.0f;
  }

  acc = waveReduce(acc);
  if (lane == 0) {
    float v = acc + b1[row];
    h[row] = v > 0.0f ? v : 0.0f;
  }
}

// ---------------------------------------------------------------------------
// Kernel 3: z_ego = W2 @ h + b2 (1 row/wave) fused with per-pair rotation.
// ---------------------------------------------------------------------------
__global__ __launch_bounds__(256) void k_z_rot(const float* __restrict__ W,
                                               const float* __restrict__ x,
                                               const float* __restrict__ b,
                                               const float* __restrict__ velW,
                                               const float* __restrict__ vel,
                                               float* __restrict__ zego,
                                               float* __restrict__ zflat) {
  __shared__ float zs[4];
  int lane = threadIdx.x & 63;
  int wave = threadIdx.x >> 6;
  int row = blockIdx.x * 4 + wave;
  const fx4* __restrict__ Wr = (const fx4*)(W + (size_t)row * HIDDEN);
  const fx4* __restrict__ xv = (const fx4*)x;
  float acc = 0.0f;
  #pragma unroll 4
  for (int k = lane; k < HIDDEN / 4; k += 64) {
    fx4 w = ntload4(Wr + k); fx4 v = xv[k];
    acc += w.x * v.x + w.y * v.y + w.z * v.z + w.w * v.w;
  }
  acc = waveReduce(acc);
  if (lane == 0) {
    float v = acc + b[row];
    zego[row] = v;
    zs[wave] = v;
  }
  __syncthreads();
  if (threadIdx.x < 2) {
    int m = blockIdx.x * 2 + threadIdx.x;      // pair index
    float xx = zs[2 * threadIdx.x];
    float yy = zs[2 * threadIdx.x + 1];
    float th = velW[2 * m] * vel[0] + velW[2 * m + 1] * vel[1];
    float s, c;
    sincosf(th, &s, &c);
    zflat[2 * m]     = c * xx - s * yy;
    zflat[2 * m + 1] = s * xx + c * yy;
  }
}

// ---------------------------------------------------------------------------
// Kernel 4: h_new = tanh(W_tc@z_flat + [W_ht@h_tc if h_tc != 0]);
//           z_fb = z_flat + 0.1*sigmoid(g_nrt)*h_new.  1 row/wave.
// ---------------------------------------------------------------------------
__global__ __launch_bounds__(256) void k_hnew(const float* __restrict__ Wtc,
                                              const float* __restrict__ Wht,
                                              const float* __restrict__ zflat,
                                              const float* __restrict__ htc,
                                              const float* __restrict__ gnrt,
                                              const int* __restrict__ ntc,
                                              float* __restrict__ zfb) {
  int lane = threadIdx.x & 63;
  int row = blockIdx.x * 4 + (threadIdx.x >> 6);
  const fx4* __restrict__ Ar = (const fx4*)(Wtc + (size_t)row * PHASE);
  const fx4* __restrict__ xv = (const fx4*)zflat;
  float acc = 0.0f;
  #pragma unroll 4
  for (int k = lane; k < PHASE / 4; k += 64) {
    fx4 a = ntload4(Ar + k); fx4 v = xv[k];
    acc += a.x * v.x + a.y * v.y + a.z * v.z + a.w * v.w;
  }
  if (*ntc) {  // h_tc has nonzeros: add the W_ht stream
    const fx4* __restrict__ Br = (const fx4*)(Wht + (size_t)row * PHASE);
    const fx4* __restrict__ hv = (const fx4*)htc;
    #pragma unroll 4
    for (int k = lane; k < PHASE / 4; k += 64) {
      fx4 bb = ntload4(Br + k); fx4 u = hv[k];
      acc += bb.x * u.x + bb.y * u.y + bb.z * u.z + bb.w * u.w;
    }
  }
  acc = waveReduce(acc);
  if (lane == 0) {
    float hn = tanhf(acc);
    float sg = 1.0f / (1.0f + expf(-gnrt[row]));
    zfb[row] = zflat[row] + 0.1f * sg * hn;
  }
}

// ---------------------------------------------------------------------------
// Kernel 5: single-block deterministic norms + final where/rescale.
// ---------------------------------------------------------------------------
__global__ __launch_bounds__(1024) void k_out(const float* __restrict__ zego,
                                              const float* __restrict__ zfb,
                                              float* __restrict__ out) {
  __shared__ float s0[16], s1[16];
  int t = threadIdx.x;
  int lane = t & 63, wave = t >> 6;
  float a = 0.0f, bsum = 0.0f;
  #pragma unroll
  for (int i = 0; i < PHASE / 1024; ++i) {
    float xe = zego[t + i * 1024]; a += xe * xe;
    float xf = zfb[t + i * 1024];  bsum += xf * xf;
  }
  a = waveReduce(a);
  bsum = waveReduce(bsum);
  if (lane == 0) { s0[wave] = a; s1[wave] = bsum; }
  __syncthreads();
  if (t == 0) {
    float ta = 0.0f, tb = 0.0f;
    #pragma unroll
    for (int w = 0; w < 16; ++w) { ta += s0[w]; tb += s1[w]; }
    s0[0] = ta; s1[0] = tb;
  }
  __syncthreads();
  float tn = sqrtf(s0[0]);
  float cn = sqrtf(s1[0]);
  float scale = tn / fmaxf(cn, NORM_EPS);
  #pragma unroll
  for (int i = 0; i < PHASE / 1024; ++i) {
    float v = zfb[t + i * 1024];
    float r = v * scale;
    float o = (cn > NORM_EPS) ? r : v;
    o = (tn > NORM_EPS) ? o : 0.0f;
    out[t + i * 1024] = o;
  }
}

extern "C" void kernel_launch(void* const* d_in, const int* in_sizes, int n_in,
                              void* d_out, int out_size, void* d_ws, size_t ws_size,
                              hipStream_t stream) {
  const float* sdr  = (const float*)d_in[0];
  const float* vel  = (const float*)d_in[1];
  const float* W1   = (const float*)d_in[2];
  const float* b1   = (const float*)d_in[3];
  const float* W2   = (const float*)d_in[4];
  const float* b2   = (const float*)d_in[5];
  const float* velW = (const float*)d_in[6];
  const float* Wtc  = (const float*)d_in[7];
  const float* Wht  = (const float*)d_in[8];
  const float* gnrt = (const float*)d_in[9];
  const float* htc  = (const float*)d_in[10];
  float* out = (float*)d_out;

  char* ws = (char*)d_ws;
  unsigned int* masks  = (unsigned int*)ws;               // 16 KB
  int*          ngrp   = (int*)(ws + 16384);
  int*          ntc    = (int*)(ws + 16384 + 64);
  unsigned int* packed = (unsigned int*)(ws + 16384 + 128);   // 16 KB
  float* h     = (float*)(ws + 32768 + 256);
  float* zego  = h + HIDDEN;
  float* zflat = zego + PHASE;
  float* zfb   = zflat + PHASE;

  k_masks<<<NGRP / 256, 256, 0, stream>>>(sdr, masks);
  k_emit<<<1, 1024, 0, stream>>>(masks, htc, packed, ngrp, ntc);
  k_h<<<HIDDEN / 4, 256, 0, stream>>>(W1, b1, packed, ngrp, h);
  k_z_rot<<<PHASE / 4, 256, 0, stream>>>(W2, h, b2, velW, vel, zego, zflat);
  k_hnew<<<PHASE / 4, 256, 0, stream>>>(Wtc, Wht, zflat, htc, gnrt, ntc, zfb);
  k_out<<<1, 1024, 0, stream>>>(zego, zfb, out);
}